// Round 9
// baseline (3568.248 us; speedup 1.0000x reference)
//
#include <hip/hip_runtime.h>
#include <hip/hip_fp16.h>
#include <math.h>

#define HDIM 2048
#define G4   (4 * HDIM)   // 8192 gate rows
#define NBLK 256          // persistent grid — full machine (1 block/CU)
#define TPB  512          // threads per block (8 waves, 2 waves/SIMD)
#define NWORD 2048        // 4-B tagged h words per buffer (1 fp16 each)

// __builtin_amdgcn_cvt_pkrtz / __builtin_amdgcn_fdot2 use the __fp16 vector
// type (NOT _Float16 — they don't implicitly convert).
typedef __fp16 h2_t __attribute__((ext_vector_type(2)));

__device__ __forceinline__ float fast_sigmoid(float x) {
    return 1.0f / (1.0f + __expf(-x));
}
__device__ __forceinline__ float fast_tanh(float x) {
    return 1.0f - 2.0f / (1.0f + __expf(2.0f * x));
}
__device__ __forceinline__ h2_t pk2(float a, float b) {
#if __has_builtin(__builtin_amdgcn_cvt_pkrtz)
    return __builtin_amdgcn_cvt_pkrtz(a, b);
#else
    return h2_t{(__fp16)a, (__fp16)b};
#endif
}

__device__ __forceinline__ unsigned wld(const unsigned* p) {
    return __hip_atomic_load(p, __ATOMIC_RELAXED, __HIP_MEMORY_SCOPE_AGENT);
}

// ---------------------------------------------------------------------------
// prep: zero the tagged word buffers (tag 0 = invalid). 16 x 256 covers 4096.
// ---------------------------------------------------------------------------
__global__ __launch_bounds__(256) void prep_slots(unsigned* __restrict__ slots) {
    int i = blockIdx.x * blockDim.x + threadIdx.x;
    if (i < 2 * NWORD) slots[i] = 0u;
}

// ---------------------------------------------------------------------------
// Fallback-path kernels (round-2 proven pipeline), used only if the
// cooperative launch is rejected.
// ---------------------------------------------------------------------------
__global__ __launch_bounds__(256) void prep_small(const float* __restrict__ bih,
                                                  const float* __restrict__ bhh,
                                                  float* __restrict__ bsum,
                                                  float* __restrict__ c) {
    int i = blockIdx.x * blockDim.x + threadIdx.x;
    if (i < G4) bsum[i] = bih[i] + bhh[i];
    if (i < HDIM) c[i] = 0.0f;
}

__global__ __launch_bounds__(256) void prep_wsum_h(const float* __restrict__ Wih,
                                                   const float* __restrict__ Whh,
                                                   __half* __restrict__ Wsum) {
    const int n8 = (G4 * HDIM) / 8;
    int idx = blockIdx.x * blockDim.x + threadIdx.x;
    int stride = gridDim.x * blockDim.x;
    const float4* a = (const float4*)Wih;
    const float4* b = (const float4*)Whh;
    for (int i = idx; i < n8; i += stride) {
        float4 a0 = a[2 * i], a1 = a[2 * i + 1];
        float4 b0 = b[2 * i], b1 = b[2 * i + 1];
        __half h[8];
        h[0] = __float2half(a0.x + b0.x);
        h[1] = __float2half(a0.y + b0.y);
        h[2] = __float2half(a0.z + b0.z);
        h[3] = __float2half(a0.w + b0.w);
        h[4] = __float2half(a1.x + b1.x);
        h[5] = __float2half(a1.y + b1.y);
        h[6] = __float2half(a1.z + b1.z);
        h[7] = __float2half(a1.w + b1.w);
        ((uint4*)Wsum)[i] = *(const uint4*)h;
    }
}

__global__ __launch_bounds__(256) void lstm_step_f32(const float* __restrict__ x,
                                                     const float* __restrict__ W,
                                                     const float* __restrict__ bsum,
                                                     float* __restrict__ c,
                                                     float* __restrict__ h_out) {
    __shared__ float gates[4][8];
    const int tid  = threadIdx.x;
    const int wave = tid >> 6;
    const int lane = tid & 63;
    const int j0   = blockIdx.x * 8;

    float4 xv[8];
    const float4* xp = (const float4*)x;
#pragma unroll
    for (int k = 0; k < 8; ++k) xv[k] = xp[lane + 64 * k];

    float acc[8];
#pragma unroll
    for (int j8 = 0; j8 < 8; ++j8) {
        const int R = wave * HDIM + j0 + j8;
        const float4* wr = (const float4*)(W + (size_t)R * HDIM);
        float a = 0.0f;
#pragma unroll
        for (int k = 0; k < 8; ++k) {
            float4 wv = wr[lane + 64 * k];
            a += wv.x * xv[k].x + wv.y * xv[k].y + wv.z * xv[k].z + wv.w * xv[k].w;
        }
        acc[j8] = a;
    }
#pragma unroll
    for (int j8 = 0; j8 < 8; ++j8) {
        float a = acc[j8];
#pragma unroll
        for (int off = 32; off > 0; off >>= 1) a += __shfl_down(a, off, 64);
        if (lane == 0) gates[wave][j8] = a + bsum[wave * HDIM + j0 + j8];
    }
    __syncthreads();
    if (tid < 8) {
        const int j = j0 + tid;
        const float si = 1.0f / (1.0f + expf(-gates[0][tid]));
        const float so = 1.0f / (1.0f + expf(-gates[3][tid]));
        const float tg = tanhf(gates[2][tid]);
        const float cn = si * tg;  // c0 = 0
        c[j]     = cn;
        h_out[j] = so * tanhf(cn);
    }
}

__global__ __launch_bounds__(256) void lstm_step_h(const float* __restrict__ x,
                                                   const __half* __restrict__ W,
                                                   const float* __restrict__ bsum,
                                                   float* __restrict__ c,
                                                   float* __restrict__ h_out) {
    __shared__ float gates[4][8];
    const int tid  = threadIdx.x;
    const int wave = tid >> 6;
    const int lane = tid & 63;
    const int j0   = blockIdx.x * 8;

    float xv[32];
    const float4* xp = (const float4*)x;
#pragma unroll
    for (int k = 0; k < 4; ++k) {
        float4 a = xp[k * 128 + lane * 2];
        float4 b = xp[k * 128 + lane * 2 + 1];
        xv[k * 8 + 0] = a.x; xv[k * 8 + 1] = a.y; xv[k * 8 + 2] = a.z; xv[k * 8 + 3] = a.w;
        xv[k * 8 + 4] = b.x; xv[k * 8 + 5] = b.y; xv[k * 8 + 6] = b.z; xv[k * 8 + 7] = b.w;
    }
    float acc[8];
#pragma unroll
    for (int j8 = 0; j8 < 8; ++j8) {
        const int R = wave * HDIM + j0 + j8;
        const uint4* wr = (const uint4*)(W + (size_t)R * HDIM);
        float a = 0.0f;
#pragma unroll
        for (int k = 0; k < 4; ++k) {
            uint4 wv = wr[k * 64 + lane];
            const __half* hh = (const __half*)&wv;
#pragma unroll
            for (int e = 0; e < 8; ++e)
                a = fmaf(__half2float(hh[e]), xv[k * 8 + e], a);
        }
        acc[j8] = a;
    }
#pragma unroll
    for (int j8 = 0; j8 < 8; ++j8) {
        float a = acc[j8];
#pragma unroll
        for (int off = 32; off > 0; off >>= 1) a += __shfl_down(a, off, 64);
        if (lane == 0) gates[wave][j8] = a + bsum[wave * HDIM + j0 + j8];
    }
    __syncthreads();
    if (tid < 8) {
        const int j = j0 + tid;
        const float si = 1.0f / (1.0f + expf(-gates[0][tid]));
        const float sf = 1.0f / (1.0f + expf(-gates[1][tid]));
        const float so = 1.0f / (1.0f + expf(-gates[3][tid]));
        const float tg = tanhf(gates[2][tid]);
        const float cn = sf * c[j] + si * tg;
        c[j]     = cn;
        h_out[j] = so * tanhf(cn);
    }
}

// ---------------------------------------------------------------------------
// Persistent kernel, r16: r15 compute structure (256 blocks x 8 waves, 1 h
// per wave, w[4][4], 64 fdot2, r1 dependent poll, barrier-before-dot) with
// the publish chain DE-AGGREGATED:
//   - slot = 4-B word: (tag16 << 16) | fp16(h). 2048 words/buffer = 8 KB =
//     128 cache lines — SAME line footprint as r1's dense layout (r3's
//     regression came from 8x line count, not from per-wave publish per se);
//   - each wave's lane0 publishes its own word IMMEDIATELY after pointwise:
//     no h16 LDS hop, no barrier #2, no wave0 aggregation — the publish
//     leaves ~150-250 cycles earlier and is no longer coupled to the
//     block's slowest wave;
//   - consumer: thread polls 4 contiguous words (16 B; line count unchanged,
//     4x4-B loads instead of 2x8-B), strips tags, packs pairs into the same
//     lds_x layout — dot/reduce/pointwise unchanged;
//   - out[] write double-buffered (h_outf[2][8]) and moved behind barrier
//     #1 so it stays race-free without barrier #2.
// ---------------------------------------------------------------------------
__global__ __launch_bounds__(TPB, 2) void lstm_persist(const float* __restrict__ X,
                                                       const float* __restrict__ Wih,
                                                       const float* __restrict__ Whh,
                                                       const float* __restrict__ bih,
                                                       const float* __restrict__ bhh,
                                                       float* __restrict__ out,
                                                       unsigned* __restrict__ slots,
                                                       int T) {
    const int tid  = threadIdx.x;
    const int wave = tid >> 6;        // 0..7
    const int lane = tid & 63;
    const int jH   = blockIdx.x * 8 + wave;  // this wave's h index
    const int myword = blockIdx.x * 8 + wave; // word this wave publishes

    // ---- X columns for this lane (e-major, matches weight layout) ----
    float xv[32];
    {
        const float4* xp = (const float4*)X;
#pragma unroll
        for (int e = 0; e < 4; ++e) {
            float4 a = xp[(lane + 64 * e) * 2];
            float4 b = xp[(lane + 64 * e) * 2 + 1];
            xv[e * 8 + 0] = a.x; xv[e * 8 + 1] = a.y; xv[e * 8 + 2] = a.z; xv[e * 8 + 3] = a.w;
            xv[e * 8 + 4] = b.x; xv[e * 8 + 5] = b.y; xv[e * 8 + 6] = b.z; xv[e * 8 + 7] = b.w;
        }
    }

    // ---- weight convert + step-0 dot, fused (4 rows: one per gate) ----
    uint4 w[4][4];
    float bias[4], acc[4];
#pragma unroll
    for (int g = 0; g < 4; ++g) {
        const size_t R = (size_t)g * HDIM + jH;
        const float4* ri = (const float4*)(Wih + R * HDIM);
        const float4* rh = (const float4*)(Whh + R * HDIM);
        float a0acc = 0.0f;
#pragma unroll
        for (int e = 0; e < 4; ++e) {
            float4 a0 = ri[(lane + 64 * e) * 2];
            float4 a1 = ri[(lane + 64 * e) * 2 + 1];
            float4 b0 = rh[(lane + 64 * e) * 2];
            float4 b1 = rh[(lane + 64 * e) * 2 + 1];
            a0acc += a0.x * xv[e * 8 + 0] + a0.y * xv[e * 8 + 1]
                   + a0.z * xv[e * 8 + 2] + a0.w * xv[e * 8 + 3]
                   + a1.x * xv[e * 8 + 4] + a1.y * xv[e * 8 + 5]
                   + a1.z * xv[e * 8 + 6] + a1.w * xv[e * 8 + 7];
            h2_t p0 = pk2(a0.x + b0.x, a0.y + b0.y);
            h2_t p1 = pk2(a0.z + b0.z, a0.w + b0.w);
            h2_t p2 = pk2(a1.x + b1.x, a1.y + b1.y);
            h2_t p3 = pk2(a1.z + b1.z, a1.w + b1.w);
            w[g][e] = make_uint4(__builtin_bit_cast(unsigned, p0),
                                 __builtin_bit_cast(unsigned, p1),
                                 __builtin_bit_cast(unsigned, p2),
                                 __builtin_bit_cast(unsigned, p3));
        }
        acc[g]  = a0acc;
        bias[g] = bih[R] + bhh[R];
    }

    __shared__ __align__(16) unsigned lds_x[2][NWORD / 2];  // double-buffered h pairs
    __shared__ float h_outf[2][8];                          // staged fp32 outputs

    float cc = 0.0f;

    // ---- step 0: butterfly + pointwise (c0 = 0) + per-wave publish tag 1 --
#pragma unroll
    for (int g = 0; g < 4; ++g)
#pragma unroll
        for (int off = 32; off > 0; off >>= 1)
            acc[g] += __shfl_xor(acc[g], off, 64);
    {
        const float si = fast_sigmoid(acc[0] + bias[0]);
        const float tg = fast_tanh(acc[2] + bias[2]);
        const float so = fast_sigmoid(acc[3] + bias[3]);
        cc = si * tg;
        const float h = so * fast_tanh(cc);
        if (lane == 0) {
            const unsigned h16 = __builtin_bit_cast(unsigned, pk2(h, h)) & 0xffffu;
            __hip_atomic_store(&slots[myword], (1u << 16) | h16,
                               __ATOMIC_RELAXED, __HIP_MEMORY_SCOPE_AGENT);
            h_outf[0][wave] = h;
        }
    }

    // ---- steps 1..T-1 ----
    for (int t = 1; t < T; ++t) {
        const int buf = (t - 1) & 1;
        const unsigned* sl = slots + (size_t)buf * NWORD + 4 * (size_t)tid;
        const unsigned tg = (unsigned)t;

        // r1 dependent poll on this thread's 4 contiguous tagged words
        unsigned v0 = wld(sl + 0), v1 = wld(sl + 1), v2 = wld(sl + 2), v3 = wld(sl + 3);
        int spin = 0;
        while (((v0 >> 16) != tg) | ((v1 >> 16) != tg) |
               ((v2 >> 16) != tg) | ((v3 >> 16) != tg)) {
            if (spin++) __builtin_amdgcn_s_sleep(1);
            if ((v0 >> 16) != tg) v0 = wld(sl + 0);
            if ((v1 >> 16) != tg) v1 = wld(sl + 1);
            if ((v2 >> 16) != tg) v2 = wld(sl + 2);
            if ((v3 >> 16) != tg) v3 = wld(sl + 3);
        }
        lds_x[buf][2 * tid]     = (v0 & 0xffffu) | (v1 << 16);
        lds_x[buf][2 * tid + 1] = (v2 & 0xffffu) | (v3 << 16);
        __syncthreads();   // the ONE barrier: LDS x-buffer fully staged

        // Deferred, coalesced out[] write for step t-1 — placed AFTER the
        // barrier so all waves' h_outf[(t-1)&1] writes are ordered; the
        // double buffer makes the next overwrite (end of step t+1) safe.
        if (wave == 1 && lane < 8) {
            out[(size_t)(t - 1) * HDIM + blockIdx.x * 8 + lane] =
                h_outf[(t - 1) & 1][lane];
        }

        // dot: 4 gate rows x 32 cols per lane
        float a2[4] = {0.f, 0.f, 0.f, 0.f};
#pragma unroll
        for (int e = 0; e < 4; ++e) {
            const uint4 xq = *(const uint4*)&lds_x[buf][(lane + 64 * e) * 4];
            const unsigned xs[4] = {xq.x, xq.y, xq.z, xq.w};
#pragma unroll
            for (int p = 0; p < 4; ++p) {
                const h2_t xh = __builtin_bit_cast(h2_t, xs[p]);
#pragma unroll
                for (int g = 0; g < 4; ++g) {
                    const h2_t* wh = (const h2_t*)&w[g][e];
#if __has_builtin(__builtin_amdgcn_fdot2)
                    a2[g] = __builtin_amdgcn_fdot2(wh[p], xh, a2[g], false);
#else
                    a2[g] = fmaf((float)wh[p][0], (float)xh[0],
                                 fmaf((float)wh[p][1], (float)xh[1], a2[g]));
#endif
                }
            }
        }

        // butterfly reduce: every lane ends with all 4 gate sums
#pragma unroll
        for (int g = 0; g < 4; ++g)
#pragma unroll
            for (int off = 32; off > 0; off >>= 1)
                a2[g] += __shfl_xor(a2[g], off, 64);

        // wave-uniform pointwise (one h per wave)
        const float si = fast_sigmoid(a2[0] + bias[0]);
        const float sf = fast_sigmoid(a2[1] + bias[1]);
        const float tg2 = fast_tanh(a2[2] + bias[2]);
        const float so = fast_sigmoid(a2[3] + bias[3]);
        cc = sf * cc + si * tg2;
        const float h = so * fast_tanh(cc);

        // per-wave IMMEDIATE publish (tag t+1, buf t&1): 4-B tagged word,
        // dense layout — no LDS hop, no second barrier, no aggregation.
        if (lane == 0) {
            const unsigned h16 = __builtin_bit_cast(unsigned, pk2(h, h)) & 0xffffu;
            __hip_atomic_store(&slots[(size_t)(t & 1) * NWORD + myword],
                               ((unsigned)(t + 1) << 16) | h16,
                               __ATOMIC_RELAXED, __HIP_MEMORY_SCOPE_AGENT);
            h_outf[t & 1][wave] = h;
        }
    }

    // final step's output (order all waves' last h_outf writes first)
    __syncthreads();
    if (wave == 1 && lane < 8) {
        out[(size_t)(T - 1) * HDIM + blockIdx.x * 8 + lane] =
            h_outf[(T - 1) & 1][lane];
    }
}

// ---------------------------------------------------------------------------
extern "C" void kernel_launch(void* const* d_in, const int* in_sizes, int n_in,
                              void* d_out, int out_size, void* d_ws, size_t ws_size,
                              hipStream_t stream) {
    const float* X   = (const float*)d_in[0];
    const float* Wih = (const float*)d_in[1];
    const float* Whh = (const float*)d_in[2];
    const float* bih = (const float*)d_in[3];
    const float* bhh = (const float*)d_in[4];
    float* out = (float*)d_out;

    int T = out_size / HDIM;  // 512

    // ws layout (shared with fallback): [Wsum fp16 33.55MB][bsum][c][slots]
    const size_t wsum_bytes = (size_t)G4 * HDIM * sizeof(__half);
    char* ws = (char*)d_ws;
    __half* Wsum = (__half*)ws;
    float*  bsum = (float*)(ws + wsum_bytes);
    float*  c    = bsum + G4;
    unsigned* slots = (unsigned*)(c + HDIM);

    prep_slots<<<16, 256, 0, stream>>>(slots);

    // Single self-contained persistent kernel (weight convert + all T steps).
    void* args[] = {(void*)&X, (void*)&Wih, (void*)&Whh, (void*)&bih,
                    (void*)&bhh, (void*)&out, (void*)&slots, (void*)&T};
    hipError_t err = hipLaunchCooperativeKernel((const void*)lstm_persist,
                                                dim3(NBLK), dim3(TPB), args, 0, stream);
    if (err != hipSuccess) {
        // Fallback: proven round-2 pipeline.
        prep_small<<<(G4 + 255) / 256, 256, 0, stream>>>(bih, bhh, bsum, c);
        prep_wsum_h<<<2048, 256, 0, stream>>>(Wih, Whh, Wsum);
        lstm_step_f32<<<256, 256, 0, stream>>>(X, Wih, bsum, c, out);
        for (int t = 1; t < T; ++t) {
            const float* hprev = out + (size_t)(t - 1) * HDIM;
            float* hnext = out + (size_t)t * HDIM;
            lstm_step_h<<<256, 256, 0, stream>>>(hprev, Wsum, bsum, c, hnext);
        }
    }
}

// Round 10
// 1534.735 us; speedup vs baseline: 2.3250x; 2.3250x over previous
//
#include <hip/hip_runtime.h>
#include <hip/hip_fp16.h>
#include <math.h>

#define HDIM 2048
#define G4   (4 * HDIM)   // 8192 gate rows
#define NBLK 256          // persistent grid — full machine (1 block/CU)
#define TPB  512          // threads per block (8 waves, 2 waves/SIMD)
#define NSLOT 1024        // h slots per buffer (2 fp16 per slot)

// __builtin_amdgcn_cvt_pkrtz / __builtin_amdgcn_fdot2 use the __fp16 vector
// type (NOT _Float16 — they don't implicitly convert).
typedef __fp16 h2_t __attribute__((ext_vector_type(2)));

__device__ __forceinline__ float fast_sigmoid(float x) {
    return 1.0f / (1.0f + __expf(-x));
}
__device__ __forceinline__ float fast_tanh(float x) {
    return 1.0f - 2.0f / (1.0f + __expf(2.0f * x));
}
__device__ __forceinline__ h2_t pk2(float a, float b) {
#if __has_builtin(__builtin_amdgcn_cvt_pkrtz)
    return __builtin_amdgcn_cvt_pkrtz(a, b);
#else
    return h2_t{(__fp16)a, (__fp16)b};
#endif
}

// ---------------------------------------------------------------------------
// prep: zero the tagged slot buffers (tag 0 = invalid). 8 x 256 covers 2048.
// ---------------------------------------------------------------------------
__global__ __launch_bounds__(256) void prep_slots(unsigned long long* __restrict__ slots) {
    int i = blockIdx.x * blockDim.x + threadIdx.x;
    if (i < 2 * NSLOT) slots[i] = 0ull;
}

// ---------------------------------------------------------------------------
// Fallback-path kernels (round-2 proven pipeline), used only if the
// cooperative launch is rejected.
// ---------------------------------------------------------------------------
__global__ __launch_bounds__(256) void prep_small(const float* __restrict__ bih,
                                                  const float* __restrict__ bhh,
                                                  float* __restrict__ bsum,
                                                  float* __restrict__ c) {
    int i = blockIdx.x * blockDim.x + threadIdx.x;
    if (i < G4) bsum[i] = bih[i] + bhh[i];
    if (i < HDIM) c[i] = 0.0f;
}

__global__ __launch_bounds__(256) void prep_wsum_h(const float* __restrict__ Wih,
                                                   const float* __restrict__ Whh,
                                                   __half* __restrict__ Wsum) {
    const int n8 = (G4 * HDIM) / 8;
    int idx = blockIdx.x * blockDim.x + threadIdx.x;
    int stride = gridDim.x * blockDim.x;
    const float4* a = (const float4*)Wih;
    const float4* b = (const float4*)Whh;
    for (int i = idx; i < n8; i += stride) {
        float4 a0 = a[2 * i], a1 = a[2 * i + 1];
        float4 b0 = b[2 * i], b1 = b[2 * i + 1];
        __half h[8];
        h[0] = __float2half(a0.x + b0.x);
        h[1] = __float2half(a0.y + b0.y);
        h[2] = __float2half(a0.z + b0.z);
        h[3] = __float2half(a0.w + b0.w);
        h[4] = __float2half(a1.x + b1.x);
        h[5] = __float2half(a1.y + b1.y);
        h[6] = __float2half(a1.z + b1.z);
        h[7] = __float2half(a1.w + b1.w);
        ((uint4*)Wsum)[i] = *(const uint4*)h;
    }
}

__global__ __launch_bounds__(256) void lstm_step_f32(const float* __restrict__ x,
                                                     const float* __restrict__ W,
                                                     const float* __restrict__ bsum,
                                                     float* __restrict__ c,
                                                     float* __restrict__ h_out) {
    __shared__ float gates[4][8];
    const int tid  = threadIdx.x;
    const int wave = tid >> 6;
    const int lane = tid & 63;
    const int j0   = blockIdx.x * 8;

    float4 xv[8];
    const float4* xp = (const float4*)x;
#pragma unroll
    for (int k = 0; k < 8; ++k) xv[k] = xp[lane + 64 * k];

    float acc[8];
#pragma unroll
    for (int j8 = 0; j8 < 8; ++j8) {
        const int R = wave * HDIM + j0 + j8;
        const float4* wr = (const float4*)(W + (size_t)R * HDIM);
        float a = 0.0f;
#pragma unroll
        for (int k = 0; k < 8; ++k) {
            float4 wv = wr[lane + 64 * k];
            a += wv.x * xv[k].x + wv.y * xv[k].y + wv.z * xv[k].z + wv.w * xv[k].w;
        }
        acc[j8] = a;
    }
#pragma unroll
    for (int j8 = 0; j8 < 8; ++j8) {
        float a = acc[j8];
#pragma unroll
        for (int off = 32; off > 0; off >>= 1) a += __shfl_down(a, off, 64);
        if (lane == 0) gates[wave][j8] = a + bsum[wave * HDIM + j0 + j8];
    }
    __syncthreads();
    if (tid < 8) {
        const int j = j0 + tid;
        const float si = 1.0f / (1.0f + expf(-gates[0][tid]));
        const float so = 1.0f / (1.0f + expf(-gates[3][tid]));
        const float tg = tanhf(gates[2][tid]);
        const float cn = si * tg;  // c0 = 0
        c[j]     = cn;
        h_out[j] = so * tanhf(cn);
    }
}

__global__ __launch_bounds__(256) void lstm_step_h(const float* __restrict__ x,
                                                   const __half* __restrict__ W,
                                                   const float* __restrict__ bsum,
                                                   float* __restrict__ c,
                                                   float* __restrict__ h_out) {
    __shared__ float gates[4][8];
    const int tid  = threadIdx.x;
    const int wave = tid >> 6;
    const int lane = tid & 63;
    const int j0   = blockIdx.x * 8;

    float xv[32];
    const float4* xp = (const float4*)x;
#pragma unroll
    for (int k = 0; k < 4; ++k) {
        float4 a = xp[k * 128 + lane * 2];
        float4 b = xp[k * 128 + lane * 2 + 1];
        xv[k * 8 + 0] = a.x; xv[k * 8 + 1] = a.y; xv[k * 8 + 2] = a.z; xv[k * 8 + 3] = a.w;
        xv[k * 8 + 4] = b.x; xv[k * 8 + 5] = b.y; xv[k * 8 + 6] = b.z; xv[k * 8 + 7] = b.w;
    }
    float acc[8];
#pragma unroll
    for (int j8 = 0; j8 < 8; ++j8) {
        const int R = wave * HDIM + j0 + j8;
        const uint4* wr = (const uint4*)(W + (size_t)R * HDIM);
        float a = 0.0f;
#pragma unroll
        for (int k = 0; k < 4; ++k) {
            uint4 wv = wr[k * 64 + lane];
            const __half* hh = (const __half*)&wv;
#pragma unroll
            for (int e = 0; e < 8; ++e)
                a = fmaf(__half2float(hh[e]), xv[k * 8 + e], a);
        }
        acc[j8] = a;
    }
#pragma unroll
    for (int j8 = 0; j8 < 8; ++j8) {
        float a = acc[j8];
#pragma unroll
        for (int off = 32; off > 0; off >>= 1) a += __shfl_down(a, off, 64);
        if (lane == 0) gates[wave][j8] = a + bsum[wave * HDIM + j0 + j8];
    }
    __syncthreads();
    if (tid < 8) {
        const int j = j0 + tid;
        const float si = 1.0f / (1.0f + expf(-gates[0][tid]));
        const float sf = 1.0f / (1.0f + expf(-gates[1][tid]));
        const float so = 1.0f / (1.0f + expf(-gates[3][tid]));
        const float tg = tanhf(gates[2][tid]);
        const float cn = sf * c[j] + si * tg;
        c[j]     = cn;
        h_out[j] = so * tanhf(cn);
    }
}

// ---------------------------------------------------------------------------
// Persistent kernel, r18: r15 (best: 1400 us steady) with the block-internal
// publish chain shortened WITHOUT violating the single-writer-line law
// (r7/r3/r16 all proved multi-writer slot lines churn the TCC):
//   - barrier #2 + h16[] hop replaced by an LDS TAG-SPIN: each wave's lane0
//     writes (tag<<16)|h16 to h_sig[parity][wave]; wave0 lanes<4 spin on
//     their two words and emit the SAME single 32-B aggregated burst as r15.
//     Publish departs at (last wave's pointwise + LDS RTT) instead of
//     (barrier arrival + release + read). Waves 1-7 start the next poll
//     immediately.
//   - reduce folded: 4 gate partials -> 1 value/lane (3 shfl) + 4-level
//     butterfly (4 shfl) + 4 broadcast shfl = 11 shfl vs 24; pointwise does
//     ONE expf/lane (tanh via 2*sigmoid(2s)-1, bit-identical formula).
// Invariants: wave0 publishes tag t+1 only after all 8 waves finished step t
// (exactly what barrier #2 proved); lds_x overwrite safety rests on barrier
// #1 alone (stage(t) follows detect(t) follows barrier#1(t-1) follows all
// dots of t-2). out[] staging double-buffered, written after barrier #1.
// ---------------------------------------------------------------------------
__global__ __launch_bounds__(TPB, 2) void lstm_persist(const float* __restrict__ X,
                                                       const float* __restrict__ Wih,
                                                       const float* __restrict__ Whh,
                                                       const float* __restrict__ bih,
                                                       const float* __restrict__ bhh,
                                                       float* __restrict__ out,
                                                       unsigned long long* __restrict__ slots,
                                                       int T) {
    const int tid  = threadIdx.x;
    const int wave = tid >> 6;        // 0..7
    const int lane = tid & 63;
    const int jH   = blockIdx.x * 8 + wave;  // this wave's h index

    __shared__ __align__(16) unsigned lds_x[2][NSLOT];  // double-buffered h pairs
    __shared__ unsigned h_sig[2][8];                    // (tag<<16)|h16 per wave
    __shared__ float h_outf[2][8];                      // staged fp32 outputs

    if (tid < 16) ((unsigned*)h_sig)[tid] = 0u;  // ordered by prologue barrier

    if (wave == 0) __builtin_amdgcn_s_setprio(1);  // publisher wave priority

    // ---- X columns for this lane (e-major, matches weight layout) ----
    float xv[32];
    {
        const float4* xp = (const float4*)X;
#pragma unroll
        for (int e = 0; e < 4; ++e) {
            float4 a = xp[(lane + 64 * e) * 2];
            float4 b = xp[(lane + 64 * e) * 2 + 1];
            xv[e * 8 + 0] = a.x; xv[e * 8 + 1] = a.y; xv[e * 8 + 2] = a.z; xv[e * 8 + 3] = a.w;
            xv[e * 8 + 4] = b.x; xv[e * 8 + 5] = b.y; xv[e * 8 + 6] = b.z; xv[e * 8 + 7] = b.w;
        }
    }

    // ---- weight convert + step-0 dot, fused (4 rows: one per gate) ----
    uint4 w[4][4];
    float bias[4], acc[4];
#pragma unroll
    for (int g = 0; g < 4; ++g) {
        const size_t R = (size_t)g * HDIM + jH;
        const float4* ri = (const float4*)(Wih + R * HDIM);
        const float4* rh = (const float4*)(Whh + R * HDIM);
        float a0acc = 0.0f;
#pragma unroll
        for (int e = 0; e < 4; ++e) {
            float4 a0 = ri[(lane + 64 * e) * 2];
            float4 a1 = ri[(lane + 64 * e) * 2 + 1];
            float4 b0 = rh[(lane + 64 * e) * 2];
            float4 b1 = rh[(lane + 64 * e) * 2 + 1];
            a0acc += a0.x * xv[e * 8 + 0] + a0.y * xv[e * 8 + 1]
                   + a0.z * xv[e * 8 + 2] + a0.w * xv[e * 8 + 3]
                   + a1.x * xv[e * 8 + 4] + a1.y * xv[e * 8 + 5]
                   + a1.z * xv[e * 8 + 6] + a1.w * xv[e * 8 + 7];
            h2_t p0 = pk2(a0.x + b0.x, a0.y + b0.y);
            h2_t p1 = pk2(a0.z + b0.z, a0.w + b0.w);
            h2_t p2 = pk2(a1.x + b1.x, a1.y + b1.y);
            h2_t p3 = pk2(a1.z + b1.z, a1.w + b1.w);
            w[g][e] = make_uint4(__builtin_bit_cast(unsigned, p0),
                                 __builtin_bit_cast(unsigned, p1),
                                 __builtin_bit_cast(unsigned, p2),
                                 __builtin_bit_cast(unsigned, p3));
        }
        acc[g]  = a0acc;
        bias[g] = bih[R] + bhh[R];
    }

    // Orders the h_sig zero-init before any tag write (and the heavy weight
    // loads are behind us). One-time barrier.
    __syncthreads();

    // bias for THIS lane's folded gate (g = lane&3), compile-time indexed
    const float bias_g = (lane & 2) ? ((lane & 1) ? bias[3] : bias[2])
                                    : ((lane & 1) ? bias[1] : bias[0]);
    const bool  isg    = ((lane & 3) == 2);   // tanh gate
    const int   bse    = lane & ~3;           // 4-lane group base

    float cc = 0.0f;

    // ---- step 0: folded reduce + pointwise (c0 = 0) + publish tag 1 ----
    {
        float z01 = (lane & 1) ? acc[1] : acc[0];
        float u01 = (lane & 1) ? acc[0] : acc[1];
        z01 += __shfl_xor(u01, 1, 64);
        float z23 = (lane & 1) ? acc[3] : acc[2];
        float u23 = (lane & 1) ? acc[2] : acc[3];
        z23 += __shfl_xor(u23, 1, 64);
        float y = (lane & 2) ? z23 : z01;
        float v = (lane & 2) ? z01 : z23;
        y += __shfl_xor(v, 2, 64);
#pragma unroll
        for (int off = 4; off < 64; off <<= 1) y += __shfl_xor(y, off, 64);

        const float s   = y + bias_g;
        const float arg = isg ? 2.0f * s : s;
        const float sg  = fast_sigmoid(arg);
        const float act = isg ? 2.0f * sg - 1.0f : sg;
        const float gi = __shfl(act, bse + 0, 64);
        const float gg = __shfl(act, bse + 2, 64);
        const float go = __shfl(act, bse + 3, 64);
        cc = gi * gg;
        const float h = go * fast_tanh(cc);
        if (lane == 0) {
            const unsigned h16v = __builtin_bit_cast(unsigned, pk2(h, h)) & 0xffffu;
            __hip_atomic_store(&h_sig[0][wave], (1u << 16) | h16v,
                               __ATOMIC_RELAXED, __HIP_MEMORY_SCOPE_WORKGROUP);
            h_outf[0][wave] = h;
        }
        if (wave == 0 && lane < 4) {
            unsigned va, vb;
            do { va = __hip_atomic_load(&h_sig[0][2 * lane], __ATOMIC_RELAXED,
                                        __HIP_MEMORY_SCOPE_WORKGROUP); } while ((va >> 16) != 1u);
            do { vb = __hip_atomic_load(&h_sig[0][2 * lane + 1], __ATOMIC_RELAXED,
                                        __HIP_MEMORY_SCOPE_WORKGROUP); } while ((vb >> 16) != 1u);
            const unsigned payload = (va & 0xffffu) | (vb << 16);
            unsigned long long pkv = (1ull << 32) | (unsigned long long)payload;
            __hip_atomic_store(&slots[blockIdx.x * 4 + lane], pkv,
                               __ATOMIC_RELAXED, __HIP_MEMORY_SCOPE_AGENT);
        }
    }

    // ---- steps 1..T-1 ----
    for (int t = 1; t < T; ++t) {
        const int buf = (t - 1) & 1;
        const unsigned long long* sl = slots + (size_t)buf * NSLOT;
        const unsigned tg = (unsigned)t;
        const int s0 = tid;
        const int s1 = tid + 512;

        // r1 dependent poll (proven optimal), two slots per thread
        unsigned long long v0 = __hip_atomic_load(&sl[s0], __ATOMIC_RELAXED,
                                                  __HIP_MEMORY_SCOPE_AGENT);
        unsigned long long v1 = __hip_atomic_load(&sl[s1], __ATOMIC_RELAXED,
                                                  __HIP_MEMORY_SCOPE_AGENT);
        int spin = 0;
        while (((unsigned)(v0 >> 32) != tg) | ((unsigned)(v1 >> 32) != tg)) {
            if (spin++) __builtin_amdgcn_s_sleep(1);
            if ((unsigned)(v0 >> 32) != tg)
                v0 = __hip_atomic_load(&sl[s0], __ATOMIC_RELAXED,
                                       __HIP_MEMORY_SCOPE_AGENT);
            if ((unsigned)(v1 >> 32) != tg)
                v1 = __hip_atomic_load(&sl[s1], __ATOMIC_RELAXED,
                                       __HIP_MEMORY_SCOPE_AGENT);
        }
        lds_x[buf][s0] = (unsigned)v0;
        lds_x[buf][s1] = (unsigned)v1;
        __syncthreads();   // barrier #1: LDS x-buffer fully staged

        // Deferred, coalesced out[] write for step t-1 (ordered by barrier
        // #1; double buffer makes the end-of-step-(t+1) overwrite safe).
        if (wave == 1 && lane < 8) {
            out[(size_t)(t - 1) * HDIM + blockIdx.x * 8 + lane] =
                h_outf[(t - 1) & 1][lane];
        }

        // dot: 4 gate rows x 32 cols per lane
        float a2[4] = {0.f, 0.f, 0.f, 0.f};
#pragma unroll
        for (int e = 0; e < 4; ++e) {
            const uint4 xq = *(const uint4*)&lds_x[buf][(lane + 64 * e) * 4];
            const unsigned xs[4] = {xq.x, xq.y, xq.z, xq.w};
#pragma unroll
            for (int p = 0; p < 4; ++p) {
                const h2_t xh = __builtin_bit_cast(h2_t, xs[p]);
#pragma unroll
                for (int g = 0; g < 4; ++g) {
                    const h2_t* wh = (const h2_t*)&w[g][e];
#if __has_builtin(__builtin_amdgcn_fdot2)
                    a2[g] = __builtin_amdgcn_fdot2(wh[p], xh, a2[g], false);
#else
                    a2[g] = fmaf((float)wh[p][0], (float)xh[0],
                                 fmaf((float)wh[p][1], (float)xh[1], a2[g]));
#endif
                }
            }
        }

        // folded reduce: 3 shfl to 1 value/lane (gate = lane&3), then 4-level
        // butterfly — every lane ends with the full sum of its gate.
        float z01 = (lane & 1) ? a2[1] : a2[0];
        float u01 = (lane & 1) ? a2[0] : a2[1];
        z01 += __shfl_xor(u01, 1, 64);
        float z23 = (lane & 1) ? a2[3] : a2[2];
        float u23 = (lane & 1) ? a2[2] : a2[3];
        z23 += __shfl_xor(u23, 1, 64);
        float y = (lane & 2) ? z23 : z01;
        float v = (lane & 2) ? z01 : z23;
        y += __shfl_xor(v, 2, 64);
#pragma unroll
        for (int off = 4; off < 64; off <<= 1) y += __shfl_xor(y, off, 64);

        // pointwise: ONE expf/lane for the gate activation, broadcast in the
        // 4-lane group, then c/h (redundant per lane, as before).
        const float s   = y + bias_g;
        const float arg = isg ? 2.0f * s : s;
        const float sg  = fast_sigmoid(arg);
        const float act = isg ? 2.0f * sg - 1.0f : sg;   // tanh = 2σ(2s)−1
        const float gi = __shfl(act, bse + 0, 64);
        const float gf = __shfl(act, bse + 1, 64);
        const float gg = __shfl(act, bse + 2, 64);
        const float go = __shfl(act, bse + 3, 64);
        cc = gf * cc + gi * gg;
        const float h = go * fast_tanh(cc);

        // lane0 drops tagged h into LDS; NO barrier — wave0 tag-spins.
        if (lane == 0) {
            const unsigned h16v = __builtin_bit_cast(unsigned, pk2(h, h)) & 0xffffu;
            __hip_atomic_store(&h_sig[t & 1][wave],
                               ((unsigned)(t + 1) << 16) | h16v,
                               __ATOMIC_RELAXED, __HIP_MEMORY_SCOPE_WORKGROUP);
            h_outf[t & 1][wave] = h;
        }

        // wave0 lanes<4: spin on the two h_sig words, then the SAME single
        // 32-B aggregated single-writer burst as r15 (tag t+1, buf t&1).
        if (wave == 0 && lane < 4) {
            const unsigned tagv = (unsigned)(t + 1);
            unsigned va, vb;
            do { va = __hip_atomic_load(&h_sig[t & 1][2 * lane], __ATOMIC_RELAXED,
                                        __HIP_MEMORY_SCOPE_WORKGROUP); } while ((va >> 16) != tagv);
            do { vb = __hip_atomic_load(&h_sig[t & 1][2 * lane + 1], __ATOMIC_RELAXED,
                                        __HIP_MEMORY_SCOPE_WORKGROUP); } while ((vb >> 16) != tagv);
            const unsigned payload = (va & 0xffffu) | (vb << 16);
            unsigned long long pkv = ((unsigned long long)tagv << 32)
                                   | (unsigned long long)payload;
            __hip_atomic_store(&slots[(size_t)(t & 1) * NSLOT + blockIdx.x * 4 + lane],
                               pkv, __ATOMIC_RELAXED, __HIP_MEMORY_SCOPE_AGENT);
        }
    }

    // final step's output (order all waves' last h_outf writes first)
    __syncthreads();
    if (wave == 1 && lane < 8) {
        out[(size_t)(T - 1) * HDIM + blockIdx.x * 8 + lane] =
            h_outf[(T - 1) & 1][lane];
    }
}

// ---------------------------------------------------------------------------
extern "C" void kernel_launch(void* const* d_in, const int* in_sizes, int n_in,
                              void* d_out, int out_size, void* d_ws, size_t ws_size,
                              hipStream_t stream) {
    const float* X   = (const float*)d_in[0];
    const float* Wih = (const float*)d_in[1];
    const float* Whh = (const float*)d_in[2];
    const float* bih = (const float*)d_in[3];
    const float* bhh = (const float*)d_in[4];
    float* out = (float*)d_out;

    int T = out_size / HDIM;  // 512

    // ws layout (shared with fallback): [Wsum fp16 33.55MB][bsum][c][slots]
    const size_t wsum_bytes = (size_t)G4 * HDIM * sizeof(__half);
    char* ws = (char*)d_ws;
    __half* Wsum = (__half*)ws;
    float*  bsum = (float*)(ws + wsum_bytes);
    float*  c    = bsum + G4;
    unsigned long long* slots = (unsigned long long*)(c + HDIM);

    prep_slots<<<8, 256, 0, stream>>>(slots);

    // Single self-contained persistent kernel (weight convert + all T steps).
    void* args[] = {(void*)&X, (void*)&Wih, (void*)&Whh, (void*)&bih,
                    (void*)&bhh, (void*)&out, (void*)&slots, (void*)&T};
    hipError_t err = hipLaunchCooperativeKernel((const void*)lstm_persist,
                                                dim3(NBLK), dim3(TPB), args, 0, stream);
    if (err != hipSuccess) {
        // Fallback: proven round-2 pipeline.
        prep_small<<<(G4 + 255) / 256, 256, 0, stream>>>(bih, bhh, bsum, c);
        prep_wsum_h<<<2048, 256, 0, stream>>>(Wih, Whh, Wsum);
        lstm_step_f32<<<256, 256, 0, stream>>>(X, Wih, bsum, c, out);
        for (int t = 1; t < T; ++t) {
            const float* hprev = out + (size_t)(t - 1) * HDIM;
            float* hnext = out + (size_t)t * HDIM;
            lstm_step_h<<<256, 256, 0, stream>>>(hprev, Wsum, bsum, c, hnext);
        }
    }
}

// Round 11
// 1504.306 us; speedup vs baseline: 2.3720x; 1.0202x over previous
//
#include <hip/hip_runtime.h>
#include <hip/hip_fp16.h>
#include <math.h>

#define HDIM 2048
#define G4   (4 * HDIM)   // 8192 gate rows
#define NBLK 256          // persistent grid — full machine (1 block/CU)
#define TPB  512          // threads per block (8 waves, 2 waves/SIMD)
#define NSLOT 1024        // h slots per buffer (2 fp16 per slot)

// __builtin_amdgcn_cvt_pkrtz / __builtin_amdgcn_fdot2 use the __fp16 vector
// type (NOT _Float16 — they don't implicitly convert).
typedef __fp16 h2_t __attribute__((ext_vector_type(2)));

__device__ __forceinline__ float fast_sigmoid(float x) {
    return 1.0f / (1.0f + __expf(-x));
}
__device__ __forceinline__ float fast_tanh(float x) {
    return 1.0f - 2.0f / (1.0f + __expf(2.0f * x));
}
__device__ __forceinline__ h2_t pk2(float a, float b) {
#if __has_builtin(__builtin_amdgcn_cvt_pkrtz)
    return __builtin_amdgcn_cvt_pkrtz(a, b);
#else
    return h2_t{(__fp16)a, (__fp16)b};
#endif
}

// ---------------------------------------------------------------------------
// prep: zero the tagged slot buffers (tag 0 = invalid). 8 x 256 covers 2048.
// ---------------------------------------------------------------------------
__global__ __launch_bounds__(256) void prep_slots(unsigned long long* __restrict__ slots) {
    int i = blockIdx.x * blockDim.x + threadIdx.x;
    if (i < 2 * NSLOT) slots[i] = 0ull;
}

// ---------------------------------------------------------------------------
// Fallback-path kernels (round-2 proven pipeline), used only if the
// cooperative launch is rejected.
// ---------------------------------------------------------------------------
__global__ __launch_bounds__(256) void prep_small(const float* __restrict__ bih,
                                                  const float* __restrict__ bhh,
                                                  float* __restrict__ bsum,
                                                  float* __restrict__ c) {
    int i = blockIdx.x * blockDim.x + threadIdx.x;
    if (i < G4) bsum[i] = bih[i] + bhh[i];
    if (i < HDIM) c[i] = 0.0f;
}

__global__ __launch_bounds__(256) void prep_wsum_h(const float* __restrict__ Wih,
                                                   const float* __restrict__ Whh,
                                                   __half* __restrict__ Wsum) {
    const int n8 = (G4 * HDIM) / 8;
    int idx = blockIdx.x * blockDim.x + threadIdx.x;
    int stride = gridDim.x * blockDim.x;
    const float4* a = (const float4*)Wih;
    const float4* b = (const float4*)Whh;
    for (int i = idx; i < n8; i += stride) {
        float4 a0 = a[2 * i], a1 = a[2 * i + 1];
        float4 b0 = b[2 * i], b1 = b[2 * i + 1];
        __half h[8];
        h[0] = __float2half(a0.x + b0.x);
        h[1] = __float2half(a0.y + b0.y);
        h[2] = __float2half(a0.z + b0.z);
        h[3] = __float2half(a0.w + b0.w);
        h[4] = __float2half(a1.x + b1.x);
        h[5] = __float2half(a1.y + b1.y);
        h[6] = __float2half(a1.z + b1.z);
        h[7] = __float2half(a1.w + b1.w);
        ((uint4*)Wsum)[i] = *(const uint4*)h;
    }
}

__global__ __launch_bounds__(256) void lstm_step_f32(const float* __restrict__ x,
                                                     const float* __restrict__ W,
                                                     const float* __restrict__ bsum,
                                                     float* __restrict__ c,
                                                     float* __restrict__ h_out) {
    __shared__ float gates[4][8];
    const int tid  = threadIdx.x;
    const int wave = tid >> 6;
    const int lane = tid & 63;
    const int j0   = blockIdx.x * 8;

    float4 xv[8];
    const float4* xp = (const float4*)x;
#pragma unroll
    for (int k = 0; k < 8; ++k) xv[k] = xp[lane + 64 * k];

    float acc[8];
#pragma unroll
    for (int j8 = 0; j8 < 8; ++j8) {
        const int R = wave * HDIM + j0 + j8;
        const float4* wr = (const float4*)(W + (size_t)R * HDIM);
        float a = 0.0f;
#pragma unroll
        for (int k = 0; k < 8; ++k) {
            float4 wv = wr[lane + 64 * k];
            a += wv.x * xv[k].x + wv.y * xv[k].y + wv.z * xv[k].z + wv.w * xv[k].w;
        }
        acc[j8] = a;
    }
#pragma unroll
    for (int j8 = 0; j8 < 8; ++j8) {
        float a = acc[j8];
#pragma unroll
        for (int off = 32; off > 0; off >>= 1) a += __shfl_down(a, off, 64);
        if (lane == 0) gates[wave][j8] = a + bsum[wave * HDIM + j0 + j8];
    }
    __syncthreads();
    if (tid < 8) {
        const int j = j0 + tid;
        const float si = 1.0f / (1.0f + expf(-gates[0][tid]));
        const float so = 1.0f / (1.0f + expf(-gates[3][tid]));
        const float tg = tanhf(gates[2][tid]);
        const float cn = si * tg;  // c0 = 0
        c[j]     = cn;
        h_out[j] = so * tanhf(cn);
    }
}

__global__ __launch_bounds__(256) void lstm_step_h(const float* __restrict__ x,
                                                   const __half* __restrict__ W,
                                                   const float* __restrict__ bsum,
                                                   float* __restrict__ c,
                                                   float* __restrict__ h_out) {
    __shared__ float gates[4][8];
    const int tid  = threadIdx.x;
    const int wave = tid >> 6;
    const int lane = tid & 63;
    const int j0   = blockIdx.x * 8;

    float xv[32];
    const float4* xp = (const float4*)x;
#pragma unroll
    for (int k = 0; k < 4; ++k) {
        float4 a = xp[k * 128 + lane * 2];
        float4 b = xp[k * 128 + lane * 2 + 1];
        xv[k * 8 + 0] = a.x; xv[k * 8 + 1] = a.y; xv[k * 8 + 2] = a.z; xv[k * 8 + 3] = a.w;
        xv[k * 8 + 4] = b.x; xv[k * 8 + 5] = b.y; xv[k * 8 + 6] = b.z; xv[k * 8 + 7] = b.w;
    }
    float acc[8];
#pragma unroll
    for (int j8 = 0; j8 < 8; ++j8) {
        const int R = wave * HDIM + j0 + j8;
        const uint4* wr = (const uint4*)(W + (size_t)R * HDIM);
        float a = 0.0f;
#pragma unroll
        for (int k = 0; k < 4; ++k) {
            uint4 wv = wr[k * 64 + lane];
            const __half* hh = (const __half*)&wv;
#pragma unroll
            for (int e = 0; e < 8; ++e)
                a = fmaf(__half2float(hh[e]), xv[k * 8 + e], a);
        }
        acc[j8] = a;
    }
#pragma unroll
    for (int j8 = 0; j8 < 8; ++j8) {
        float a = acc[j8];
#pragma unroll
        for (int off = 32; off > 0; off >>= 1) a += __shfl_down(a, off, 64);
        if (lane == 0) gates[wave][j8] = a + bsum[wave * HDIM + j0 + j8];
    }
    __syncthreads();
    if (tid < 8) {
        const int j = j0 + tid;
        const float si = 1.0f / (1.0f + expf(-gates[0][tid]));
        const float sf = 1.0f / (1.0f + expf(-gates[1][tid]));
        const float so = 1.0f / (1.0f + expf(-gates[3][tid]));
        const float tg = tanhf(gates[2][tid]);
        const float cn = sf * c[j] + si * tg;
        c[j]     = cn;
        h_out[j] = so * tanhf(cn);
    }
}

// ---------------------------------------------------------------------------
// Persistent kernel, r19 == r15 (session optimum: 1517 us, steady 1400).
// Final configuration, locked in after 11 structural experiments:
//   - 256 blocks x 512 threads (full machine, 1 block/CU, 2 waves/SIMD);
//     per-wave: 1 h, w[4][4] fp16 weights in registers, 64 fdot2/step.
//     (r14/r15: the only 2 wins — serial compute + register-fit; r1-r13's
//     128-VGPR cap was spilling w[] to scratch every step.)
//   - r1 dependent poll with s_sleep (beat pipelined r13 and scout r11);
//     2 slots/thread, 8-B tagged words, dense 128-line layout.
//   - single-transaction aggregated publish: wave0 lanes<4 emit one 32-B
//     tagged burst (multi-writer slot lines proven 2.4x toxic in r3/r16;
//     exchange-vs-store neutral in r12).
//   - two barriers/step; block-internal chain proven fully hidden (r18:
//     -40% reduce/pointwise VALU = no period change).
// Remaining period (~2.74 us/step) = 2 cross-die coherence traversals +
// detect quantization + E[max] tail over 256 blocks — the structural floor
// of a per-step globally-synchronized recurrence on this fabric.
// ---------------------------------------------------------------------------
__global__ __launch_bounds__(TPB, 2) void lstm_persist(const float* __restrict__ X,
                                                       const float* __restrict__ Wih,
                                                       const float* __restrict__ Whh,
                                                       const float* __restrict__ bih,
                                                       const float* __restrict__ bhh,
                                                       float* __restrict__ out,
                                                       unsigned long long* __restrict__ slots,
                                                       int T) {
    const int tid  = threadIdx.x;
    const int wave = tid >> 6;        // 0..7
    const int lane = tid & 63;
    const int jH   = blockIdx.x * 8 + wave;  // this wave's h index

    if (wave == 0) __builtin_amdgcn_s_setprio(1);  // publisher wave priority

    // ---- X columns for this lane (e-major, matches weight layout) ----
    float xv[32];
    {
        const float4* xp = (const float4*)X;
#pragma unroll
        for (int e = 0; e < 4; ++e) {
            float4 a = xp[(lane + 64 * e) * 2];
            float4 b = xp[(lane + 64 * e) * 2 + 1];
            xv[e * 8 + 0] = a.x; xv[e * 8 + 1] = a.y; xv[e * 8 + 2] = a.z; xv[e * 8 + 3] = a.w;
            xv[e * 8 + 4] = b.x; xv[e * 8 + 5] = b.y; xv[e * 8 + 6] = b.z; xv[e * 8 + 7] = b.w;
        }
    }

    // ---- weight convert + step-0 dot, fused (4 rows: one per gate) ----
    uint4 w[4][4];
    float bias[4], acc[4];
#pragma unroll
    for (int g = 0; g < 4; ++g) {
        const size_t R = (size_t)g * HDIM + jH;
        const float4* ri = (const float4*)(Wih + R * HDIM);
        const float4* rh = (const float4*)(Whh + R * HDIM);
        float a0acc = 0.0f;
#pragma unroll
        for (int e = 0; e < 4; ++e) {
            float4 a0 = ri[(lane + 64 * e) * 2];
            float4 a1 = ri[(lane + 64 * e) * 2 + 1];
            float4 b0 = rh[(lane + 64 * e) * 2];
            float4 b1 = rh[(lane + 64 * e) * 2 + 1];
            a0acc += a0.x * xv[e * 8 + 0] + a0.y * xv[e * 8 + 1]
                   + a0.z * xv[e * 8 + 2] + a0.w * xv[e * 8 + 3]
                   + a1.x * xv[e * 8 + 4] + a1.y * xv[e * 8 + 5]
                   + a1.z * xv[e * 8 + 6] + a1.w * xv[e * 8 + 7];
            h2_t p0 = pk2(a0.x + b0.x, a0.y + b0.y);
            h2_t p1 = pk2(a0.z + b0.z, a0.w + b0.w);
            h2_t p2 = pk2(a1.x + b1.x, a1.y + b1.y);
            h2_t p3 = pk2(a1.z + b1.z, a1.w + b1.w);
            w[g][e] = make_uint4(__builtin_bit_cast(unsigned, p0),
                                 __builtin_bit_cast(unsigned, p1),
                                 __builtin_bit_cast(unsigned, p2),
                                 __builtin_bit_cast(unsigned, p3));
        }
        acc[g]  = a0acc;
        bias[g] = bih[R] + bhh[R];
    }

    __shared__ __align__(16) unsigned lds_x[2][NSLOT];  // double-buffered h pairs
    __shared__ unsigned short h16[8];                   // per-wave fp16 h
    __shared__ float h_outf[8];                         // block's fp32 outputs (staged)

    float cc = 0.0f;

    // ---- step 0: butterfly + pointwise (c0 = 0) + publish tag 1, buf 0 ----
#pragma unroll
    for (int g = 0; g < 4; ++g)
#pragma unroll
        for (int off = 32; off > 0; off >>= 1)
            acc[g] += __shfl_xor(acc[g], off, 64);
    {
        const float si = fast_sigmoid(acc[0] + bias[0]);
        const float tg = fast_tanh(acc[2] + bias[2]);
        const float so = fast_sigmoid(acc[3] + bias[3]);
        cc = si * tg;
        const float h = so * fast_tanh(cc);
        if (lane == 0) {
            h16[wave] = (unsigned short)(__builtin_bit_cast(unsigned, pk2(h, h)) & 0xffffu);
            h_outf[wave] = h;   // staged; written to out at t=1 poll
        }
    }
    __syncthreads();
    if (wave == 0 && lane < 4) {
        const unsigned payload = (unsigned)h16[2 * lane]
                               | ((unsigned)h16[2 * lane + 1] << 16);
        unsigned long long pkv = (1ull << 32) | (unsigned long long)payload;
        __hip_atomic_store(&slots[blockIdx.x * 4 + lane], pkv,
                           __ATOMIC_RELAXED, __HIP_MEMORY_SCOPE_AGENT);
    }

    // ---- steps 1..T-1 ----
    for (int t = 1; t < T; ++t) {
        // Deferred, coalesced out[] write for step t-1 (proven neutral in r8;
        // ordered by the previous step's barrier).
        if (wave == 1 && lane < 8) {
            out[(size_t)(t - 1) * HDIM + blockIdx.x * 8 + lane] = h_outf[lane];
        }

        const int buf = (t - 1) & 1;
        const unsigned long long* sl = slots + (size_t)buf * NSLOT;
        const unsigned tg = (unsigned)t;
        const int s0 = tid;
        const int s1 = tid + 512;

        // r1 dependent poll (proven optimal in r13 A/B), two slots per thread
        unsigned long long v0 = __hip_atomic_load(&sl[s0], __ATOMIC_RELAXED,
                                                  __HIP_MEMORY_SCOPE_AGENT);
        unsigned long long v1 = __hip_atomic_load(&sl[s1], __ATOMIC_RELAXED,
                                                  __HIP_MEMORY_SCOPE_AGENT);
        int spin = 0;
        while (((unsigned)(v0 >> 32) != tg) | ((unsigned)(v1 >> 32) != tg)) {
            if (spin++) __builtin_amdgcn_s_sleep(1);
            if ((unsigned)(v0 >> 32) != tg)
                v0 = __hip_atomic_load(&sl[s0], __ATOMIC_RELAXED,
                                       __HIP_MEMORY_SCOPE_AGENT);
            if ((unsigned)(v1 >> 32) != tg)
                v1 = __hip_atomic_load(&sl[s1], __ATOMIC_RELAXED,
                                       __HIP_MEMORY_SCOPE_AGENT);
        }
        lds_x[buf][s0] = (unsigned)v0;
        lds_x[buf][s1] = (unsigned)v1;
        __syncthreads();

        // dot: 4 gate rows x 32 cols per lane
        float a2[4] = {0.f, 0.f, 0.f, 0.f};
#pragma unroll
        for (int e = 0; e < 4; ++e) {
            const uint4 xq = *(const uint4*)&lds_x[buf][(lane + 64 * e) * 4];
            const unsigned xs[4] = {xq.x, xq.y, xq.z, xq.w};
#pragma unroll
            for (int p = 0; p < 4; ++p) {
                const h2_t xh = __builtin_bit_cast(h2_t, xs[p]);
#pragma unroll
                for (int g = 0; g < 4; ++g) {
                    const h2_t* wh = (const h2_t*)&w[g][e];
#if __has_builtin(__builtin_amdgcn_fdot2)
                    a2[g] = __builtin_amdgcn_fdot2(wh[p], xh, a2[g], false);
#else
                    a2[g] = fmaf((float)wh[p][0], (float)xh[0],
                                 fmaf((float)wh[p][1], (float)xh[1], a2[g]));
#endif
                }
            }
        }

        // butterfly reduce: every lane ends with all 4 gate sums
#pragma unroll
        for (int g = 0; g < 4; ++g)
#pragma unroll
            for (int off = 32; off > 0; off >>= 1)
                a2[g] += __shfl_xor(a2[g], off, 64);

        // wave-uniform pointwise (one h per wave)
        const float si = fast_sigmoid(a2[0] + bias[0]);
        const float sf = fast_sigmoid(a2[1] + bias[1]);
        const float tg2 = fast_tanh(a2[2] + bias[2]);
        const float so = fast_sigmoid(a2[3] + bias[3]);
        cc = sf * cc + si * tg2;
        const float h = so * fast_tanh(cc);

        if (lane == 0) {
            h16[wave] = (unsigned short)(__builtin_bit_cast(unsigned, pk2(h, h)) & 0xffffu);
            h_outf[wave] = h;   // out[] store deferred to next poll
        }
        __syncthreads();  // LDS-only drain (no vmem on this path)

        // single-wave contiguous 32-B publish (tag t+1, buf t&1)
        if (wave == 0 && lane < 4) {
            const unsigned payload = (unsigned)h16[2 * lane]
                                   | ((unsigned)h16[2 * lane + 1] << 16);
            unsigned long long pkv = ((unsigned long long)(unsigned)(t + 1) << 32)
                                   | (unsigned long long)payload;
            __hip_atomic_store(&slots[(size_t)(t & 1) * NSLOT + blockIdx.x * 4 + lane],
                               pkv, __ATOMIC_RELAXED, __HIP_MEMORY_SCOPE_AGENT);
        }
    }

    // final step's output (ordered by the last iteration's __syncthreads)
    if (wave == 1 && lane < 8) {
        out[(size_t)(T - 1) * HDIM + blockIdx.x * 8 + lane] = h_outf[lane];
    }
}

// ---------------------------------------------------------------------------
extern "C" void kernel_launch(void* const* d_in, const int* in_sizes, int n_in,
                              void* d_out, int out_size, void* d_ws, size_t ws_size,
                              hipStream_t stream) {
    const float* X   = (const float*)d_in[0];
    const float* Wih = (const float*)d_in[1];
    const float* Whh = (const float*)d_in[2];
    const float* bih = (const float*)d_in[3];
    const float* bhh = (const float*)d_in[4];
    float* out = (float*)d_out;

    int T = out_size / HDIM;  // 512

    // ws layout (shared with fallback): [Wsum fp16 33.55MB][bsum][c][slots]
    const size_t wsum_bytes = (size_t)G4 * HDIM * sizeof(__half);
    char* ws = (char*)d_ws;
    __half* Wsum = (__half*)ws;
    float*  bsum = (float*)(ws + wsum_bytes);
    float*  c    = bsum + G4;
    unsigned long long* slots = (unsigned long long*)(c + HDIM);

    prep_slots<<<8, 256, 0, stream>>>(slots);

    // Single self-contained persistent kernel (weight convert + all T steps).
    void* args[] = {(void*)&X, (void*)&Wih, (void*)&Whh, (void*)&bih,
                    (void*)&bhh, (void*)&out, (void*)&slots, (void*)&T};
    hipError_t err = hipLaunchCooperativeKernel((const void*)lstm_persist,
                                                dim3(NBLK), dim3(TPB), args, 0, stream);
    if (err != hipSuccess) {
        // Fallback: proven round-2 pipeline.
        prep_small<<<(G4 + 255) / 256, 256, 0, stream>>>(bih, bhh, bsum, c);
        prep_wsum_h<<<2048, 256, 0, stream>>>(Wih, Whh, Wsum);
        lstm_step_f32<<<256, 256, 0, stream>>>(X, Wih, bsum, c, out);
        for (int t = 1; t < T; ++t) {
            const float* hprev = out + (size_t)(t - 1) * HDIM;
            float* hnext = out + (size_t)t * HDIM;
            lstm_step_h<<<256, 256, 0, stream>>>(hprev, Wsum, bsum, c, hnext);
        }
    }
}